// Round 2
// baseline (458.219 us; speedup 1.0000x reference)
//
#include <hip/hip_runtime.h>
#include <math.h>

#define N_TOK   65536
#define HID     1024
#define NEXP    64
#define EPSF    1e-12f

// ---------------- prep: ws[0..63] = 1/||sim col||, ws[64..127] = sigmoid(gates)
__global__ __launch_bounds__(256) void prep_kernel(const float* __restrict__ sim,
                                                   const float* __restrict__ gates,
                                                   float* __restrict__ ws) {
    __shared__ float partial[4][64];
    int e = threadIdx.x & 63;
    int q = threadIdx.x >> 6;   // 0..3
    float s = 0.f;
    for (int h = q * 256; h < q * 256 + 256; ++h) {
        float v = sim[h * NEXP + e];
        s += v * v;
    }
    partial[q][e] = s;
    __syncthreads();
    if (threadIdx.x < 64) {
        float ss = partial[0][e] + partial[1][e] + partial[2][e] + partial[3][e];
        ws[e] = 1.0f / fmaxf(sqrtf(ss), EPSF);
        ws[64 + e] = 1.0f / (1.0f + expf(-gates[e]));
    }
}

// ---------------- prep2: wn[k][e] = sim[k][e] * invcol[e]  (single f32 mul,
// identical rounding to round-1's staged normalization)
__global__ __launch_bounds__(256) void prep2_kernel(const float* __restrict__ sim,
                                                    const float* __restrict__ ws_ro,
                                                    float* __restrict__ wn) {
    int idx = blockIdx.x * 256 + threadIdx.x;     // float4 index, 16384 total
    float4 v = ((const float4*)sim)[idx];
    int e = (idx & 15) * 4;
    v.x *= ws_ro[e]; v.y *= ws_ro[e + 1]; v.z *= ws_ro[e + 2]; v.w *= ws_ro[e + 3];
    ((float4*)wn)[idx] = v;
}

// ---------------- main kernel: 1 token/thread, all 64 experts, W via scalar loads
__global__ __launch_bounds__(256) void gate_scalar_kernel(const float* __restrict__ x,
                                                          const float* __restrict__ wn,
                                                          const float* __restrict__ prep,
                                                          float* __restrict__ out) {
    const int t = blockIdx.x * 256 + threadIdx.x;       // token id
    const float4* xq = (const float4*)(x + (size_t)t * HID);

    float acc[NEXP];
#pragma unroll
    for (int e = 0; e < NEXP; ++e) acc[e] = 0.f;
    float ss = 0.f;

    // 2-iteration-deep x prefetch pipeline (8 k per iteration)
    float4 p0 = xq[0], p1 = xq[1], p2 = xq[2], p3 = xq[3];

#pragma unroll 1
    for (int i = 0; i < HID / 8; ++i) {
        float4 c0 = p0, c1 = p1;
        p0 = p2; p1 = p3;
        if (i + 2 < HID / 8) { p2 = xq[2 * i + 4]; p3 = xq[2 * i + 5]; }

        float xs[8] = { c0.x, c0.y, c0.z, c0.w, c1.x, c1.y, c1.z, c1.w };
        const float* w = wn + (size_t)i * 8 * NEXP;     // uniform address -> s_load
#pragma unroll
        for (int r = 0; r < 8; ++r) {
            ss = fmaf(xs[r], xs[r], ss);
            const float* wr = w + r * NEXP;
#pragma unroll
            for (int e = 0; e < NEXP; ++e) acc[e] = fmaf(xs[r], wr[e], acc[e]);
        }
    }

    // ---- epilogue (fully thread-private) ----
    const float invx = 1.0f / fmaxf(sqrtf(ss), EPSF);
#pragma unroll
    for (int e = 0; e < NEXP; ++e) acc[e] *= invx;      // acc = logits now

    const size_t out_pre  = (size_t)N_TOK * NEXP;
    const size_t out_mask = 2 * (size_t)N_TOK * NEXP;
    const size_t row = (size_t)t * NEXP;

    int nact = 0;
#pragma unroll
    for (int e = 0; e < NEXP; ++e) nact += (acc[e] - prep[64 + e]) > 0.f;

    // pre_activation_logits (always logit - thr)
#pragma unroll
    for (int e0 = 0; e0 < NEXP; e0 += 4) {
        float4 v = make_float4(acc[e0]     - prep[64 + e0],
                               acc[e0 + 1] - prep[64 + e0 + 1],
                               acc[e0 + 2] - prep[64 + e0 + 2],
                               acc[e0 + 3] - prep[64 + e0 + 3]);
        *(float4*)&out[out_pre + row + e0] = v;
    }

    if (nact == 0) {
        // top-32 fallback: exact 32nd-largest via radix descent on order keys
        unsigned key[NEXP];
#pragma unroll
        for (int e = 0; e < NEXP; ++e) {
            unsigned u = __float_as_uint(acc[e]);
            key[e] = (u & 0x80000000u) ? ~u : (u | 0x80000000u);
        }
        unsigned cand = 0u;
#pragma unroll 1
        for (int bit = 31; bit >= 0; --bit) {
            unsigned test = cand | (1u << bit);
            int c = 0;
#pragma unroll
            for (int e = 0; e < NEXP; ++e) c += (key[e] >= test);
            if (c >= 32) cand = test;
        }
        int need = 32;
#pragma unroll
        for (int e = 0; e < NEXP; ++e) need -= (key[e] > cand);

        float probs[NEXP], mask[NEXP];
#pragma unroll
        for (int e = 0; e < NEXP; ++e) {
            bool gt = key[e] > cand;
            bool eq = key[e] == cand;
            bool sel = gt || (eq && need > 0);
            need -= eq ? 1 : 0;
            mask[e]  = sel ? 1.f : 0.f;
            probs[e] = sel ? 0.03125f : 0.f;   // gated==0 on fallback rows
        }
#pragma unroll
        for (int e0 = 0; e0 < NEXP; e0 += 4) {
            *(float4*)&out[row + e0]            = *(float4*)&probs[e0];
            *(float4*)&out[out_mask + row + e0] = *(float4*)&mask[e0];
        }
    } else {
        float m = -INFINITY;
#pragma unroll
        for (int e = 0; e < NEXP; ++e) {
            float pr = acc[e] - prep[64 + e];
            if (pr > 0.f) m = fmaxf(m, pr);
        }
        float ex[NEXP];
        float s = 0.f;
#pragma unroll
        for (int e = 0; e < NEXP; ++e) {
            float pr = acc[e] - prep[64 + e];
            ex[e] = (pr > 0.f) ? expf(pr - m) : 0.f;
            s += ex[e];
        }
        float rs = 1.0f / s;
#pragma unroll
        for (int e0 = 0; e0 < NEXP; e0 += 4) {
            float4 pv = make_float4(ex[e0] * rs, ex[e0 + 1] * rs,
                                    ex[e0 + 2] * rs, ex[e0 + 3] * rs);
            float4 mv = make_float4((acc[e0]     - prep[64 + e0])     > 0.f ? 1.f : 0.f,
                                    (acc[e0 + 1] - prep[64 + e0 + 1]) > 0.f ? 1.f : 0.f,
                                    (acc[e0 + 2] - prep[64 + e0 + 2]) > 0.f ? 1.f : 0.f,
                                    (acc[e0 + 3] - prep[64 + e0 + 3]) > 0.f ? 1.f : 0.f);
            *(float4*)&out[row + e0]            = pv;
            *(float4*)&out[out_mask + row + e0] = mv;
        }
    }
}

// ---------------- fallback (verbatim round-1 kernel, used if ws too small) ----
#define TOKB    128
#define KC      64
#define XPAD    65

__global__ __launch_bounds__(256) void gate_kernel_fb(const float* __restrict__ x,
                                                      const float* __restrict__ sim,
                                                      const float* __restrict__ prep,
                                                      float* __restrict__ out) {
    __shared__ float x_lds[TOKB][XPAD];
    __shared__ float w_lds[KC][NEXP];
    __shared__ float ss_lds[TOKB];
    __shared__ float invcol[NEXP];
    __shared__ float thr_s[NEXP];

    const int tid = threadIdx.x;
    const int base_t = blockIdx.x * TOKB;

    if (tid < NEXP) { invcol[tid] = prep[tid]; thr_s[tid] = prep[64 + tid]; }
    if (tid < TOKB) ss_lds[tid] = 0.f;

    const int g_e = tid & 7;
    const int g_t = tid >> 3;
    const int e0 = g_e * 8;
    const int t0 = g_t * 4;

    const int lt = tid >> 4;
    const int lk = (tid & 15) * 4;

    float acc[4][8];
#pragma unroll
    for (int j = 0; j < 4; ++j)
#pragma unroll
        for (int i = 0; i < 8; ++i) acc[j][i] = 0.f;

    for (int kc = 0; kc < HID; kc += KC) {
        __syncthreads();
#pragma unroll
        for (int it = 0; it < 4; ++it) {
            int flat4 = it * 256 + tid;
            int k = flat4 >> 4;
            int e = (flat4 & 15) * 4;
            float4 v = *(const float4*)&sim[(size_t)(kc + k) * NEXP + e];
            v.x *= invcol[e]; v.y *= invcol[e + 1]; v.z *= invcol[e + 2]; v.w *= invcol[e + 3];
            *(float4*)&w_lds[k][e] = v;
        }
#pragma unroll
        for (int it = 0; it < 8; ++it) {
            int t = it * 16 + lt;
            float4 v = *(const float4*)&x[(size_t)(base_t + t) * HID + kc + lk];
            x_lds[t][lk + 0] = v.x; x_lds[t][lk + 1] = v.y;
            x_lds[t][lk + 2] = v.z; x_lds[t][lk + 3] = v.w;
            float s4 = v.x * v.x + v.y * v.y + v.z * v.z + v.w * v.w;
            s4 += __shfl_xor(s4, 1, 16);
            s4 += __shfl_xor(s4, 2, 16);
            s4 += __shfl_xor(s4, 4, 16);
            s4 += __shfl_xor(s4, 8, 16);
            if ((tid & 15) == 0) ss_lds[t] += s4;
        }
        __syncthreads();
#pragma unroll 8
        for (int k = 0; k < KC; ++k) {
            float x0 = x_lds[t0 + 0][k];
            float x1 = x_lds[t0 + 1][k];
            float x2 = x_lds[t0 + 2][k];
            float x3 = x_lds[t0 + 3][k];
            float4 w0 = *(const float4*)&w_lds[k][e0];
            float4 w1 = *(const float4*)&w_lds[k][e0 + 4];
            float wv[8] = { w0.x, w0.y, w0.z, w0.w, w1.x, w1.y, w1.z, w1.w };
#pragma unroll
            for (int i = 0; i < 8; ++i) {
                acc[0][i] += x0 * wv[i];
                acc[1][i] += x1 * wv[i];
                acc[2][i] += x2 * wv[i];
                acc[3][i] += x3 * wv[i];
            }
        }
    }

    const size_t out_pre  = (size_t)N_TOK * NEXP;
    const size_t out_mask = 2 * (size_t)N_TOK * NEXP;

#pragma unroll
    for (int j = 0; j < 4; ++j) {
        int t = t0 + j;
        float inv = 1.0f / fmaxf(sqrtf(ss_lds[t]), EPSF);
        float logit[8], pre[8], gated[8];
        int active[8];
        int myact = 0;
#pragma unroll
        for (int i = 0; i < 8; ++i) {
            logit[i] = acc[j][i] * inv;
            pre[i]   = logit[i] - thr_s[e0 + i];
            gated[i] = fmaxf(pre[i], 0.f);
            active[i] = pre[i] > 0.f;
            myact += active[i];
        }
        int rowact = myact;
        rowact += __shfl_xor(rowact, 1, 8);
        rowact += __shfl_xor(rowact, 2, 8);
        rowact += __shfl_xor(rowact, 4, 8);

        float probs[8], mask[8];
        if (rowact > 0) {
            float m = -INFINITY;
#pragma unroll
            for (int i = 0; i < 8; ++i) m = fmaxf(m, active[i] ? gated[i] : -INFINITY);
            m = fmaxf(m, __shfl_xor(m, 1, 8));
            m = fmaxf(m, __shfl_xor(m, 2, 8));
            m = fmaxf(m, __shfl_xor(m, 4, 8));
            float s = 0.f;
#pragma unroll
            for (int i = 0; i < 8; ++i) {
                float ev = active[i] ? expf(gated[i] - m) : 0.f;
                probs[i] = ev; s += ev;
            }
            s += __shfl_xor(s, 1, 8);
            s += __shfl_xor(s, 2, 8);
            s += __shfl_xor(s, 4, 8);
            float rs = 1.0f / s;
#pragma unroll
            for (int i = 0; i < 8; ++i) {
                probs[i] *= rs;
                mask[i] = active[i] ? 1.f : 0.f;
            }
        } else {
            unsigned key[8];
#pragma unroll
            for (int i = 0; i < 8; ++i) {
                unsigned u = __float_as_uint(logit[i]);
                key[i] = (u & 0x80000000u) ? ~u : (u | 0x80000000u);
            }
            unsigned cand = 0u;
            for (int bit = 31; bit >= 0; --bit) {
                unsigned test = cand | (1u << bit);
                int c = 0;
#pragma unroll
                for (int i = 0; i < 8; ++i) c += (key[i] >= test);
                c += __shfl_xor(c, 1, 8);
                c += __shfl_xor(c, 2, 8);
                c += __shfl_xor(c, 4, 8);
                if (c >= 32) cand = test;
            }
            int cgt = 0;
#pragma unroll
            for (int i = 0; i < 8; ++i) cgt += (key[i] > cand);
            cgt += __shfl_xor(cgt, 1, 8);
            cgt += __shfl_xor(cgt, 2, 8);
            cgt += __shfl_xor(cgt, 4, 8);
            int need_eq = 32 - cgt;

            int eqc = 0;
#pragma unroll
            for (int i = 0; i < 8; ++i) eqc += (key[i] == cand);
            int scan = eqc, tmp;
            tmp = __shfl_up(scan, 1, 8); if (g_e >= 1) scan += tmp;
            tmp = __shfl_up(scan, 2, 8); if (g_e >= 2) scan += tmp;
            tmp = __shfl_up(scan, 4, 8); if (g_e >= 4) scan += tmp;
            int run = scan - eqc;
#pragma unroll
            for (int i = 0; i < 8; ++i) {
                int sel = (key[i] > cand) || ((key[i] == cand) && (run < need_eq));
                run += (key[i] == cand);
                mask[i]  = sel ? 1.f : 0.f;
                probs[i] = sel ? 0.03125f : 0.f;
            }
        }

        size_t row = (size_t)(base_t + t) * NEXP + e0;
        *(float4*)&out[row]                = make_float4(probs[0], probs[1], probs[2], probs[3]);
        *(float4*)&out[row + 4]            = make_float4(probs[4], probs[5], probs[6], probs[7]);
        *(float4*)&out[out_pre + row]      = make_float4(pre[0], pre[1], pre[2], pre[3]);
        *(float4*)&out[out_pre + row + 4]  = make_float4(pre[4], pre[5], pre[6], pre[7]);
        *(float4*)&out[out_mask + row]     = make_float4(mask[0], mask[1], mask[2], mask[3]);
        *(float4*)&out[out_mask + row + 4] = make_float4(mask[4], mask[5], mask[6], mask[7]);
    }
}

extern "C" void kernel_launch(void* const* d_in, const int* in_sizes, int n_in,
                              void* d_out, int out_size, void* d_ws, size_t ws_size,
                              hipStream_t stream) {
    (void)in_sizes; (void)n_in; (void)out_size;
    const float* x     = (const float*)d_in[0];
    const float* sim   = (const float*)d_in[1];
    const float* gates = (const float*)d_in[2];
    float* out = (float*)d_out;
    float* ws  = (float*)d_ws;

    hipLaunchKernelGGL(prep_kernel, dim3(1), dim3(256), 0, stream, sim, gates, ws);

    const size_t need = 512 + (size_t)HID * NEXP * sizeof(float);   // prep + normalized W
    if (ws_size >= need) {
        float* wn = ws + 128;
        hipLaunchKernelGGL(prep2_kernel, dim3((HID * NEXP / 4) / 256), dim3(256), 0, stream,
                           sim, ws, wn);
        hipLaunchKernelGGL(gate_scalar_kernel, dim3(N_TOK / 256), dim3(256), 0, stream,
                           x, wn, ws, out);
    } else {
        hipLaunchKernelGGL(gate_kernel_fb, dim3(N_TOK / TOKB), dim3(256), 0, stream,
                           x, sim, ws, out);
    }
}

// Round 3
// 398.590 us; speedup vs baseline: 1.1496x; 1.1496x over previous
//
#include <hip/hip_runtime.h>
#include <math.h>

#define N_TOK   65536
#define HID     1024
#define NEXP    64
#define EPSF    1e-12f

// ---------------- prep: ws[0..63] = 1/||sim col||, ws[64..127] = sigmoid(gates)
__global__ __launch_bounds__(256) void prep_kernel(const float* __restrict__ sim,
                                                   const float* __restrict__ gates,
                                                   float* __restrict__ ws) {
    __shared__ float partial[4][64];
    int e = threadIdx.x & 63;
    int q = threadIdx.x >> 6;   // 0..3
    float s = 0.f;
    for (int h = q * 256; h < q * 256 + 256; ++h) {
        float v = sim[h * NEXP + e];
        s += v * v;
    }
    partial[q][e] = s;
    __syncthreads();
    if (threadIdx.x < 64) {
        float ss = partial[0][e] + partial[1][e] + partial[2][e] + partial[3][e];
        ws[e] = 1.0f / fmaxf(sqrtf(ss), EPSF);
        ws[64 + e] = 1.0f / (1.0f + expf(-gates[e]));
    }
}

// ---------------- prep2: expert-block-major normalized W for scalar loads.
// wn2[(e>>3)*8192 + k*8 + (e&7)] = sim[k][e] * invcol[e]   (single f32 mul,
// identical rounding to rounds 1-2)
__global__ __launch_bounds__(256) void prep2_kernel(const float* __restrict__ sim,
                                                    const float* __restrict__ ws_ro,
                                                    float* __restrict__ wn2) {
    int idx = blockIdx.x * 256 + threadIdx.x;   // 0..65535
    int k = idx >> 6;
    int e = idx & 63;
    wn2[(size_t)(e >> 3) * 8192 + k * 8 + (e & 7)] = sim[idx] * ws_ro[e];
}

// ---------------- main kernel: 8 waves, wave = 8 experts (SGPR W), lane = token
// LDS x tile [64 tok][64 k], physical slot s of row r holds k4 = s ^ (r&7).
__global__ __launch_bounds__(512) void gate_wave_kernel(const float* __restrict__ x,
                                                        const float* __restrict__ wn2,
                                                        const float* __restrict__ prep,
                                                        float* __restrict__ out) {
    // smem: [0..8191] x double-buffer (2 x 64 x 64); epilogue overlays logits
    // [0..4607] (64 x 72). thr at [8192..8255], ss at [8256..8319].
    __shared__ __align__(16) float smem[8320];
    float* thr_lds = smem + 8192;
    float* ss_lds  = smem + 8256;

    const int tid  = threadIdx.x;
    const int lane = tid & 63;
    const int wave = __builtin_amdgcn_readfirstlane(tid >> 6);   // 0..7
    const int blk64 = blockIdx.x * 64;
    const float* wb = wn2 + (size_t)wave * 8192;   // wave-uniform -> s_load

    if (tid < 64) thr_lds[tid] = prep[64 + tid];

    // staging geometry: thread handles float4 f0 = wave*64+lane and f0+512
    const int f0 = wave * 64 + lane;     // 0..511
    const int r0 = f0 >> 4;              // rows 0..31 (pair row = r0+32)
    const int s0 = f0 & 15;
    const int k40 = s0 ^ (r0 & 7);       // (r0+32)&7 == r0&7, so same k4 for pair
    const float* g0 = x + (size_t)(blk64 + r0) * HID + k40 * 4;
    const float* g1 = x + (size_t)(blk64 + r0 + 32) * HID + k40 * 4;

    const int sw = lane & 7;             // read-side swizzle
    float acc[8];
#pragma unroll
    for (int i = 0; i < 8; ++i) acc[i] = 0.f;
    float ss = 0.f;

    // prologue: stage chunk 0
    float4 st0 = *(const float4*)(g0);
    float4 st1 = *(const float4*)(g1);
    *(float4*)&smem[r0 * 64 + s0 * 4]        = st0;
    *(float4*)&smem[(r0 + 32) * 64 + s0 * 4] = st1;
    __syncthreads();

#pragma unroll 1
    for (int c = 0; c < 16; ++c) {
        // issue next chunk's global loads (latency hides under compute)
        if (c < 15) {
            st0 = *(const float4*)(g0 + (c + 1) * 64);
            st1 = *(const float4*)(g1 + (c + 1) * 64);
        }
        const float* xrow = smem + (c & 1) * 4096 + lane * 64;
        const float* wc   = wb + c * 512;
#pragma unroll
        for (int j = 0; j < 16; ++j) {
            const float4 v = *(const float4*)(xrow + ((j ^ sw) << 2));
            const float* wk = wc + j * 32;
            const float xv[4] = { v.x, v.y, v.z, v.w };
            if (wave == 0) {   // wave-uniform branch: row-norm partials
                ss = fmaf(v.x, v.x, ss);
                ss = fmaf(v.y, v.y, ss);
                ss = fmaf(v.z, v.z, ss);
                ss = fmaf(v.w, v.w, ss);
            }
#pragma unroll
            for (int kk = 0; kk < 4; ++kk)
#pragma unroll
                for (int i = 0; i < 8; ++i)
                    acc[i] = fmaf(xv[kk], wk[kk * 8 + i], acc[i]);
        }
        // write next chunk into the other buffer (no race: disjoint buffers)
        if (c < 15) {
            const int bo = ((c + 1) & 1) * 4096;
            *(float4*)&smem[bo + r0 * 64 + s0 * 4]        = st0;
            *(float4*)&smem[bo + (r0 + 32) * 64 + s0 * 4] = st1;
        }
        __syncthreads();
    }

    // dump per-wave logits (raw dot products) into LDS [64 tok][72]
    if (wave == 0) ss_lds[lane] = ss;
    {
        float* lg = smem + lane * 72 + wave * 8;
        *(float4*)&lg[0] = make_float4(acc[0], acc[1], acc[2], acc[3]);
        *(float4*)&lg[4] = make_float4(acc[4], acc[5], acc[6], acc[7]);
    }
    __syncthreads();

    // ---- epilogue: wave w -> tokens w*8..w*8+7, 8 lanes per token ----
    const int tl2 = wave * 8 + (lane >> 3);   // local token 0..63
    const int g_e = lane & 7;                 // expert group
    const int e0 = g_e * 8;
    const int t  = blk64 + tl2;

    const float inv = 1.0f / fmaxf(sqrtf(ss_lds[tl2]), EPSF);
    float logit[8], pre[8], gated[8];
    int active[8];
    int myact = 0;
#pragma unroll
    for (int i = 0; i < 8; ++i) {
        logit[i] = smem[tl2 * 72 + e0 + i] * inv;
        pre[i]   = logit[i] - thr_lds[e0 + i];
        gated[i] = fmaxf(pre[i], 0.f);
        active[i] = pre[i] > 0.f;
        myact += active[i];
    }
    int rowact = myact;
    rowact += __shfl_xor(rowact, 1, 8);
    rowact += __shfl_xor(rowact, 2, 8);
    rowact += __shfl_xor(rowact, 4, 8);

    float probs[8], mask[8];
    if (rowact > 0) {
        float m = -INFINITY;
#pragma unroll
        for (int i = 0; i < 8; ++i) m = fmaxf(m, active[i] ? gated[i] : -INFINITY);
        m = fmaxf(m, __shfl_xor(m, 1, 8));
        m = fmaxf(m, __shfl_xor(m, 2, 8));
        m = fmaxf(m, __shfl_xor(m, 4, 8));
        float s = 0.f;
#pragma unroll
        for (int i = 0; i < 8; ++i) {
            float ev = active[i] ? expf(gated[i] - m) : 0.f;
            probs[i] = ev; s += ev;
        }
        s += __shfl_xor(s, 1, 8);
        s += __shfl_xor(s, 2, 8);
        s += __shfl_xor(s, 4, 8);
        float rs = 1.0f / s;
#pragma unroll
        for (int i = 0; i < 8; ++i) {
            probs[i] *= rs;
            mask[i] = active[i] ? 1.f : 0.f;
        }
    } else {
        // top-32 fallback: exact 32nd-largest via radix descent on order keys
        unsigned key[8];
#pragma unroll
        for (int i = 0; i < 8; ++i) {
            unsigned u = __float_as_uint(logit[i]);
            key[i] = (u & 0x80000000u) ? ~u : (u | 0x80000000u);
        }
        unsigned cand = 0u;
        for (int bit = 31; bit >= 0; --bit) {
            unsigned test = cand | (1u << bit);
            int c = 0;
#pragma unroll
            for (int i = 0; i < 8; ++i) c += (key[i] >= test);
            c += __shfl_xor(c, 1, 8);
            c += __shfl_xor(c, 2, 8);
            c += __shfl_xor(c, 4, 8);
            if (c >= 32) cand = test;
        }
        int cgt = 0;
#pragma unroll
        for (int i = 0; i < 8; ++i) cgt += (key[i] > cand);
        cgt += __shfl_xor(cgt, 1, 8);
        cgt += __shfl_xor(cgt, 2, 8);
        cgt += __shfl_xor(cgt, 4, 8);
        int need_eq = 32 - cgt;

        int eqc = 0;
#pragma unroll
        for (int i = 0; i < 8; ++i) eqc += (key[i] == cand);
        int scan = eqc, tmp;
        tmp = __shfl_up(scan, 1, 8); if (g_e >= 1) scan += tmp;
        tmp = __shfl_up(scan, 2, 8); if (g_e >= 2) scan += tmp;
        tmp = __shfl_up(scan, 4, 8); if (g_e >= 4) scan += tmp;
        int run = scan - eqc;   // ties with smaller global index
#pragma unroll
        for (int i = 0; i < 8; ++i) {
            int sel = (key[i] > cand) || ((key[i] == cand) && (run < need_eq));
            run += (key[i] == cand);
            mask[i]  = sel ? 1.f : 0.f;
            probs[i] = sel ? 0.03125f : 0.f;   // gated==0 on fallback rows
        }
    }

    const size_t out_pre  = (size_t)N_TOK * NEXP;
    const size_t out_mask = 2 * (size_t)N_TOK * NEXP;
    const size_t row = (size_t)t * NEXP + e0;
    *(float4*)&out[row]                = make_float4(probs[0], probs[1], probs[2], probs[3]);
    *(float4*)&out[row + 4]            = make_float4(probs[4], probs[5], probs[6], probs[7]);
    *(float4*)&out[out_pre + row]      = make_float4(pre[0], pre[1], pre[2], pre[3]);
    *(float4*)&out[out_pre + row + 4]  = make_float4(pre[4], pre[5], pre[6], pre[7]);
    *(float4*)&out[out_mask + row]     = make_float4(mask[0], mask[1], mask[2], mask[3]);
    *(float4*)&out[out_mask + row + 4] = make_float4(mask[4], mask[5], mask[6], mask[7]);
}

// ---------------- fallback (verbatim round-1 kernel, used only if ws too small)
#define TOKB    128
#define KC      64
#define XPAD    65

__global__ __launch_bounds__(256) void gate_kernel_fb(const float* __restrict__ x,
                                                      const float* __restrict__ sim,
                                                      const float* __restrict__ prep,
                                                      float* __restrict__ out) {
    __shared__ float x_lds[TOKB][XPAD];
    __shared__ float w_lds[KC][NEXP];
    __shared__ float ss_lds[TOKB];
    __shared__ float invcol[NEXP];
    __shared__ float thr_s[NEXP];

    const int tid = threadIdx.x;
    const int base_t = blockIdx.x * TOKB;

    if (tid < NEXP) { invcol[tid] = prep[tid]; thr_s[tid] = prep[64 + tid]; }
    if (tid < TOKB) ss_lds[tid] = 0.f;

    const int g_e = tid & 7;
    const int g_t = tid >> 3;
    const int e0 = g_e * 8;
    const int t0 = g_t * 4;

    const int lt = tid >> 4;
    const int lk = (tid & 15) * 4;

    float acc[4][8];
#pragma unroll
    for (int j = 0; j < 4; ++j)
#pragma unroll
        for (int i = 0; i < 8; ++i) acc[j][i] = 0.f;

    for (int kc = 0; kc < HID; kc += KC) {
        __syncthreads();
#pragma unroll
        for (int it = 0; it < 4; ++it) {
            int flat4 = it * 256 + tid;
            int k = flat4 >> 4;
            int e = (flat4 & 15) * 4;
            float4 v = *(const float4*)&sim[(size_t)(kc + k) * NEXP + e];
            v.x *= invcol[e]; v.y *= invcol[e + 1]; v.z *= invcol[e + 2]; v.w *= invcol[e + 3];
            *(float4*)&w_lds[k][e] = v;
        }
#pragma unroll
        for (int it = 0; it < 8; ++it) {
            int t = it * 16 + lt;
            float4 v = *(const float4*)&x[(size_t)(base_t + t) * HID + kc + lk];
            x_lds[t][lk + 0] = v.x; x_lds[t][lk + 1] = v.y;
            x_lds[t][lk + 2] = v.z; x_lds[t][lk + 3] = v.w;
            float s4 = v.x * v.x + v.y * v.y + v.z * v.z + v.w * v.w;
            s4 += __shfl_xor(s4, 1, 16);
            s4 += __shfl_xor(s4, 2, 16);
            s4 += __shfl_xor(s4, 4, 16);
            s4 += __shfl_xor(s4, 8, 16);
            if ((tid & 15) == 0) ss_lds[t] += s4;
        }
        __syncthreads();
#pragma unroll 8
        for (int k = 0; k < KC; ++k) {
            float x0 = x_lds[t0 + 0][k];
            float x1 = x_lds[t0 + 1][k];
            float x2 = x_lds[t0 + 2][k];
            float x3 = x_lds[t0 + 3][k];
            float4 w0 = *(const float4*)&w_lds[k][e0];
            float4 w1 = *(const float4*)&w_lds[k][e0 + 4];
            float wv[8] = { w0.x, w0.y, w0.z, w0.w, w1.x, w1.y, w1.z, w1.w };
#pragma unroll
            for (int i = 0; i < 8; ++i) {
                acc[0][i] += x0 * wv[i];
                acc[1][i] += x1 * wv[i];
                acc[2][i] += x2 * wv[i];
                acc[3][i] += x3 * wv[i];
            }
        }
    }

    const size_t out_pre  = (size_t)N_TOK * NEXP;
    const size_t out_mask = 2 * (size_t)N_TOK * NEXP;

#pragma unroll
    for (int j = 0; j < 4; ++j) {
        int t = t0 + j;
        float inv = 1.0f / fmaxf(sqrtf(ss_lds[t]), EPSF);
        float logit[8], pre[8], gated[8];
        int active[8];
        int myact = 0;
#pragma unroll
        for (int i = 0; i < 8; ++i) {
            logit[i] = acc[j][i] * inv;
            pre[i]   = logit[i] - thr_s[e0 + i];
            gated[i] = fmaxf(pre[i], 0.f);
            active[i] = pre[i] > 0.f;
            myact += active[i];
        }
        int rowact = myact;
        rowact += __shfl_xor(rowact, 1, 8);
        rowact += __shfl_xor(rowact, 2, 8);
        rowact += __shfl_xor(rowact, 4, 8);

        float probs[8], mask[8];
        if (rowact > 0) {
            float m = -INFINITY;
#pragma unroll
            for (int i = 0; i < 8; ++i) m = fmaxf(m, active[i] ? gated[i] : -INFINITY);
            m = fmaxf(m, __shfl_xor(m, 1, 8));
            m = fmaxf(m, __shfl_xor(m, 2, 8));
            m = fmaxf(m, __shfl_xor(m, 4, 8));
            float s = 0.f;
#pragma unroll
            for (int i = 0; i < 8; ++i) {
                float ev = active[i] ? expf(gated[i] - m) : 0.f;
                probs[i] = ev; s += ev;
            }
            s += __shfl_xor(s, 1, 8);
            s += __shfl_xor(s, 2, 8);
            s += __shfl_xor(s, 4, 8);
            float rs = 1.0f / s;
#pragma unroll
            for (int i = 0; i < 8; ++i) {
                probs[i] *= rs;
                mask[i] = active[i] ? 1.f : 0.f;
            }
        } else {
            unsigned key[8];
#pragma unroll
            for (int i = 0; i < 8; ++i) {
                unsigned u = __float_as_uint(logit[i]);
                key[i] = (u & 0x80000000u) ? ~u : (u | 0x80000000u);
            }
            unsigned cand = 0u;
            for (int bit = 31; bit >= 0; --bit) {
                unsigned test = cand | (1u << bit);
                int c = 0;
#pragma unroll
                for (int i = 0; i < 8; ++i) c += (key[i] >= test);
                c += __shfl_xor(c, 1, 8);
                c += __shfl_xor(c, 2, 8);
                c += __shfl_xor(c, 4, 8);
                if (c >= 32) cand = test;
            }
            int cgt = 0;
#pragma unroll
            for (int i = 0; i < 8; ++i) cgt += (key[i] > cand);
            cgt += __shfl_xor(cgt, 1, 8);
            cgt += __shfl_xor(cgt, 2, 8);
            cgt += __shfl_xor(cgt, 4, 8);
            int need_eq = 32 - cgt;

            int eqc = 0;
#pragma unroll
            for (int i = 0; i < 8; ++i) eqc += (key[i] == cand);
            int scan = eqc, tmp;
            tmp = __shfl_up(scan, 1, 8); if (g_e >= 1) scan += tmp;
            tmp = __shfl_up(scan, 2, 8); if (g_e >= 2) scan += tmp;
            tmp = __shfl_up(scan, 4, 8); if (g_e >= 4) scan += tmp;
            int run = scan - eqc;
#pragma unroll
            for (int i = 0; i < 8; ++i) {
                int sel = (key[i] > cand) || ((key[i] == cand) && (run < need_eq));
                run += (key[i] == cand);
                mask[i]  = sel ? 1.f : 0.f;
                probs[i] = sel ? 0.03125f : 0.f;
            }
        }

        size_t row = (size_t)(base_t + t) * NEXP + e0;
        *(float4*)&out[row]                = make_float4(probs[0], probs[1], probs[2], probs[3]);
        *(float4*)&out[row + 4]            = make_float4(probs[4], probs[5], probs[6], probs[7]);
        *(float4*)&out[out_pre + row]      = make_float4(pre[0], pre[1], pre[2], pre[3]);
        *(float4*)&out[out_pre + row + 4]  = make_float4(pre[4], pre[5], pre[6], pre[7]);
        *(float4*)&out[out_mask + row]     = make_float4(mask[0], mask[1], mask[2], mask[3]);
        *(float4*)&out[out_mask + row + 4] = make_float4(mask[4], mask[5], mask[6], mask[7]);
    }
}

extern "C" void kernel_launch(void* const* d_in, const int* in_sizes, int n_in,
                              void* d_out, int out_size, void* d_ws, size_t ws_size,
                              hipStream_t stream) {
    (void)in_sizes; (void)n_in; (void)out_size;
    const float* x     = (const float*)d_in[0];
    const float* sim   = (const float*)d_in[1];
    const float* gates = (const float*)d_in[2];
    float* out = (float*)d_out;
    float* ws  = (float*)d_ws;

    hipLaunchKernelGGL(prep_kernel, dim3(1), dim3(256), 0, stream, sim, gates, ws);

    const size_t need = 512 + (size_t)HID * NEXP * sizeof(float);   // prep + wn2
    if (ws_size >= need) {
        float* wn2 = ws + 128;
        hipLaunchKernelGGL(prep2_kernel, dim3(HID * NEXP / 256), dim3(256), 0, stream,
                           sim, ws, wn2);
        hipLaunchKernelGGL(gate_wave_kernel, dim3(N_TOK / 64), dim3(512), 0, stream,
                           x, wn2, ws, out);
    } else {
        hipLaunchKernelGGL(gate_kernel_fb, dim3(N_TOK / TOKB), dim3(256), 0, stream,
                           x, sim, ws, out);
    }
}

// Round 4
// 396.525 us; speedup vs baseline: 1.1556x; 1.0052x over previous
//
#include <hip/hip_runtime.h>
#include <math.h>

#define N_TOK   65536
#define HID     1024
#define NEXP    64
#define EPSF    1e-12f

// ---------------- prep: ws[0..63] = 1/||sim col||, ws[64..127] = sigmoid(gates)
__global__ __launch_bounds__(256) void prep_kernel(const float* __restrict__ sim,
                                                   const float* __restrict__ gates,
                                                   float* __restrict__ ws) {
    __shared__ float partial[4][64];
    int e = threadIdx.x & 63;
    int q = threadIdx.x >> 6;   // 0..3
    float s = 0.f;
    for (int h = q * 256; h < q * 256 + 256; ++h) {
        float v = sim[h * NEXP + e];
        s += v * v;
    }
    partial[q][e] = s;
    __syncthreads();
    if (threadIdx.x < 64) {
        float ss = partial[0][e] + partial[1][e] + partial[2][e] + partial[3][e];
        ws[e] = 1.0f / fmaxf(sqrtf(ss), EPSF);
        ws[64 + e] = 1.0f / (1.0f + expf(-gates[e]));
    }
}

// ---------------- prep2: expert-block-major normalized W for scalar loads.
// wn2[(e>>3)*8192 + k*8 + (e&7)] = sim[k][e] * invcol[e]   (single f32 mul,
// identical rounding to rounds 1-2)
__global__ __launch_bounds__(256) void prep2_kernel(const float* __restrict__ sim,
                                                    const float* __restrict__ ws_ro,
                                                    float* __restrict__ wn2) {
    int idx = blockIdx.x * 256 + threadIdx.x;   // 0..65535
    int k = idx >> 6;
    int e = idx & 63;
    wn2[(size_t)(e >> 3) * 8192 + k * 8 + (e & 7)] = sim[idx] * ws_ro[e];
}

// ---------------- main kernel: 8 waves, wave = 8 experts (SGPR W), lane = token
// LDS x tile [64 tok][64 k], physical slot s of row r holds k4 = s ^ (r&7).
__global__ __launch_bounds__(512) void gate_wave_kernel(const float* __restrict__ x,
                                                        const float* __restrict__ wn2,
                                                        const float* __restrict__ prep,
                                                        float* __restrict__ out) {
    // smem: [0..8191] x double-buffer (2 x 64 x 64); epilogue overlays logits
    // [0..4607] (64 x 72). thr at [8192..8255], ss at [8256..8319].
    __shared__ __align__(16) float smem[8320];
    float* thr_lds = smem + 8192;
    float* ss_lds  = smem + 8256;

    const int tid  = threadIdx.x;
    const int lane = tid & 63;
    const int wave = __builtin_amdgcn_readfirstlane(tid >> 6);   // 0..7
    const int blk64 = blockIdx.x * 64;
    const float* wb = wn2 + (size_t)wave * 8192;   // wave-uniform -> s_load

    if (tid < 64) thr_lds[tid] = prep[64 + tid];

    // staging geometry: thread handles float4 f0 = wave*64+lane and f0+512
    const int f0 = wave * 64 + lane;     // 0..511
    const int r0 = f0 >> 4;              // rows 0..31 (pair row = r0+32)
    const int s0 = f0 & 15;
    const int k40 = s0 ^ (r0 & 7);       // (r0+32)&7 == r0&7, so same k4 for pair
    const float* g0 = x + (size_t)(blk64 + r0) * HID + k40 * 4;
    const float* g1 = x + (size_t)(blk64 + r0 + 32) * HID + k40 * 4;

    const int sw = lane & 7;             // read-side swizzle
    float acc[8];
#pragma unroll
    for (int i = 0; i < 8; ++i) acc[i] = 0.f;
    float ss = 0.f;

    // prologue: stage chunk 0
    float4 st0 = *(const float4*)(g0);
    float4 st1 = *(const float4*)(g1);
    *(float4*)&smem[r0 * 64 + s0 * 4]        = st0;
    *(float4*)&smem[(r0 + 32) * 64 + s0 * 4] = st1;
    __syncthreads();

#pragma unroll 1
    for (int c = 0; c < 16; ++c) {
        // issue next chunk's global loads (latency hides under compute)
        if (c < 15) {
            st0 = *(const float4*)(g0 + (c + 1) * 64);
            st1 = *(const float4*)(g1 + (c + 1) * 64);
        }
        const float* xrow = smem + (c & 1) * 4096 + lane * 64;
        const float* wc   = wb + c * 512;
#pragma unroll
        for (int j = 0; j < 16; ++j) {
            const float4 v = *(const float4*)(xrow + ((j ^ sw) << 2));
            const float* wk = wc + j * 32;
            const float xv[4] = { v.x, v.y, v.z, v.w };
            if (wave == 0) {   // wave-uniform branch: row-norm partials
                ss = fmaf(v.x, v.x, ss);
                ss = fmaf(v.y, v.y, ss);
                ss = fmaf(v.z, v.z, ss);
                ss = fmaf(v.w, v.w, ss);
            }
#pragma unroll
            for (int kk = 0; kk < 4; ++kk)
#pragma unroll
                for (int i = 0; i < 8; ++i)
                    acc[i] = fmaf(xv[kk], wk[kk * 8 + i], acc[i]);
        }
        // write next chunk into the other buffer (no race: disjoint buffers)
        if (c < 15) {
            const int bo = ((c + 1) & 1) * 4096;
            *(float4*)&smem[bo + r0 * 64 + s0 * 4]        = st0;
            *(float4*)&smem[bo + (r0 + 32) * 64 + s0 * 4] = st1;
        }
        __syncthreads();
    }

    // dump per-wave logits (raw dot products) into LDS [64 tok][72]
    if (wave == 0) ss_lds[lane] = ss;
    {
        float* lg = smem + lane * 72 + wave * 8;
        *(float4*)&lg[0] = make_float4(acc[0], acc[1], acc[2], acc[3]);
        *(float4*)&lg[4] = make_float4(acc[4], acc[5], acc[6], acc[7]);
    }
    __syncthreads();

    // ---- epilogue: wave w -> tokens w*8..w*8+7, 8 lanes per token ----
    const int tl2 = wave * 8 + (lane >> 3);   // local token 0..63
    const int g_e = lane & 7;                 // expert group
    const int e0 = g_e * 8;
    const int t  = blk64 + tl2;

    const float inv = 1.0f / fmaxf(sqrtf(ss_lds[tl2]), EPSF);
    float logit[8], pre[8], gated[8];
    int active[8];
    int myact = 0;
#pragma unroll
    for (int i = 0; i < 8; ++i) {
        logit[i] = smem[tl2 * 72 + e0 + i] * inv;
        pre[i]   = logit[i] - thr_lds[e0 + i];
        gated[i] = fmaxf(pre[i], 0.f);
        active[i] = pre[i] > 0.f;
        myact += active[i];
    }
    int rowact = myact;
    rowact += __shfl_xor(rowact, 1, 8);
    rowact += __shfl_xor(rowact, 2, 8);
    rowact += __shfl_xor(rowact, 4, 8);

    float probs[8], mask[8];
    if (rowact > 0) {
        float m = -INFINITY;
#pragma unroll
        for (int i = 0; i < 8; ++i) m = fmaxf(m, active[i] ? gated[i] : -INFINITY);
        m = fmaxf(m, __shfl_xor(m, 1, 8));
        m = fmaxf(m, __shfl_xor(m, 2, 8));
        m = fmaxf(m, __shfl_xor(m, 4, 8));
        float s = 0.f;
#pragma unroll
        for (int i = 0; i < 8; ++i) {
            float ev = active[i] ? expf(gated[i] - m) : 0.f;
            probs[i] = ev; s += ev;
        }
        s += __shfl_xor(s, 1, 8);
        s += __shfl_xor(s, 2, 8);
        s += __shfl_xor(s, 4, 8);
        float rs = 1.0f / s;
#pragma unroll
        for (int i = 0; i < 8; ++i) {
            probs[i] *= rs;
            mask[i] = active[i] ? 1.f : 0.f;
        }
    } else {
        // top-32 fallback: exact 32nd-largest via radix descent on order keys
        unsigned key[8];
#pragma unroll
        for (int i = 0; i < 8; ++i) {
            unsigned u = __float_as_uint(logit[i]);
            key[i] = (u & 0x80000000u) ? ~u : (u | 0x80000000u);
        }
        unsigned cand = 0u;
        for (int bit = 31; bit >= 0; --bit) {
            unsigned test = cand | (1u << bit);
            int c = 0;
#pragma unroll
            for (int i = 0; i < 8; ++i) c += (key[i] >= test);
            c += __shfl_xor(c, 1, 8);
            c += __shfl_xor(c, 2, 8);
            c += __shfl_xor(c, 4, 8);
            if (c >= 32) cand = test;
        }
        int cgt = 0;
#pragma unroll
        for (int i = 0; i < 8; ++i) cgt += (key[i] > cand);
        cgt += __shfl_xor(cgt, 1, 8);
        cgt += __shfl_xor(cgt, 2, 8);
        cgt += __shfl_xor(cgt, 4, 8);
        int need_eq = 32 - cgt;

        int eqc = 0;
#pragma unroll
        for (int i = 0; i < 8; ++i) eqc += (key[i] == cand);
        int scan = eqc, tmp;
        tmp = __shfl_up(scan, 1, 8); if (g_e >= 1) scan += tmp;
        tmp = __shfl_up(scan, 2, 8); if (g_e >= 2) scan += tmp;
        tmp = __shfl_up(scan, 4, 8); if (g_e >= 4) scan += tmp;
        int run = scan - eqc;   // ties with smaller global index
#pragma unroll
        for (int i = 0; i < 8; ++i) {
            int sel = (key[i] > cand) || ((key[i] == cand) && (run < need_eq));
            run += (key[i] == cand);
            mask[i]  = sel ? 1.f : 0.f;
            probs[i] = sel ? 0.03125f : 0.f;   // gated==0 on fallback rows
        }
    }

    const size_t out_pre  = (size_t)N_TOK * NEXP;
    const size_t out_mask = 2 * (size_t)N_TOK * NEXP;
    const size_t row = (size_t)t * NEXP + e0;
    *(float4*)&out[row]                = make_float4(probs[0], probs[1], probs[2], probs[3]);
    *(float4*)&out[row + 4]            = make_float4(probs[4], probs[5], probs[6], probs[7]);
    *(float4*)&out[out_pre + row]      = make_float4(pre[0], pre[1], pre[2], pre[3]);
    *(float4*)&out[out_pre + row + 4]  = make_float4(pre[4], pre[5], pre[6], pre[7]);
    *(float4*)&out[out_mask + row]     = make_float4(mask[0], mask[1], mask[2], mask[3]);
    *(float4*)&out[out_mask + row + 4] = make_float4(mask[4], mask[5], mask[6], mask[7]);
}

// ---------------- fallback (verbatim round-1 kernel, used only if ws too small)
#define TOKB    128
#define KC      64
#define XPAD    65

__global__ __launch_bounds__(256) void gate_kernel_fb(const float* __restrict__ x,
                                                      const float* __restrict__ sim,
                                                      const float* __restrict__ prep,
                                                      float* __restrict__ out) {
    __shared__ float x_lds[TOKB][XPAD];
    __shared__ float w_lds[KC][NEXP];
    __shared__ float ss_lds[TOKB];
    __shared__ float invcol[NEXP];
    __shared__ float thr_s[NEXP];

    const int tid = threadIdx.x;
    const int base_t = blockIdx.x * TOKB;

    if (tid < NEXP) { invcol[tid] = prep[tid]; thr_s[tid] = prep[64 + tid]; }
    if (tid < TOKB) ss_lds[tid] = 0.f;

    const int g_e = tid & 7;
    const int g_t = tid >> 3;
    const int e0 = g_e * 8;
    const int t0 = g_t * 4;

    const int lt = tid >> 4;
    const int lk = (tid & 15) * 4;

    float acc[4][8];
#pragma unroll
    for (int j = 0; j < 4; ++j)
#pragma unroll
        for (int i = 0; i < 8; ++i) acc[j][i] = 0.f;

    for (int kc = 0; kc < HID; kc += KC) {
        __syncthreads();
#pragma unroll
        for (int it = 0; it < 4; ++it) {
            int flat4 = it * 256 + tid;
            int k = flat4 >> 4;
            int e = (flat4 & 15) * 4;
            float4 v = *(const float4*)&sim[(size_t)(kc + k) * NEXP + e];
            v.x *= invcol[e]; v.y *= invcol[e + 1]; v.z *= invcol[e + 2]; v.w *= invcol[e + 3];
            *(float4*)&w_lds[k][e] = v;
        }
#pragma unroll
        for (int it = 0; it < 8; ++it) {
            int t = it * 16 + lt;
            float4 v = *(const float4*)&x[(size_t)(base_t + t) * HID + kc + lk];
            x_lds[t][lk + 0] = v.x; x_lds[t][lk + 1] = v.y;
            x_lds[t][lk + 2] = v.z; x_lds[t][lk + 3] = v.w;
            float s4 = v.x * v.x + v.y * v.y + v.z * v.z + v.w * v.w;
            s4 += __shfl_xor(s4, 1, 16);
            s4 += __shfl_xor(s4, 2, 16);
            s4 += __shfl_xor(s4, 4, 16);
            s4 += __shfl_xor(s4, 8, 16);
            if ((tid & 15) == 0) ss_lds[t] += s4;
        }
        __syncthreads();
#pragma unroll 8
        for (int k = 0; k < KC; ++k) {
            float x0 = x_lds[t0 + 0][k];
            float x1 = x_lds[t0 + 1][k];
            float x2 = x_lds[t0 + 2][k];
            float x3 = x_lds[t0 + 3][k];
            float4 w0 = *(const float4*)&w_lds[k][e0];
            float4 w1 = *(const float4*)&w_lds[k][e0 + 4];
            float wv[8] = { w0.x, w0.y, w0.z, w0.w, w1.x, w1.y, w1.z, w1.w };
#pragma unroll
            for (int i = 0; i < 8; ++i) {
                acc[0][i] += x0 * wv[i];
                acc[1][i] += x1 * wv[i];
                acc[2][i] += x2 * wv[i];
                acc[3][i] += x3 * wv[i];
            }
        }
    }

    const size_t out_pre  = (size_t)N_TOK * NEXP;
    const size_t out_mask = 2 * (size_t)N_TOK * NEXP;

#pragma unroll
    for (int j = 0; j < 4; ++j) {
        int t = t0 + j;
        float inv = 1.0f / fmaxf(sqrtf(ss_lds[t]), EPSF);
        float logit[8], pre[8], gated[8];
        int active[8];
        int myact = 0;
#pragma unroll
        for (int i = 0; i < 8; ++i) {
            logit[i] = acc[j][i] * inv;
            pre[i]   = logit[i] - thr_s[e0 + i];
            gated[i] = fmaxf(pre[i], 0.f);
            active[i] = pre[i] > 0.f;
            myact += active[i];
        }
        int rowact = myact;
        rowact += __shfl_xor(rowact, 1, 8);
        rowact += __shfl_xor(rowact, 2, 8);
        rowact += __shfl_xor(rowact, 4, 8);

        float probs[8], mask[8];
        if (rowact > 0) {
            float m = -INFINITY;
#pragma unroll
            for (int i = 0; i < 8; ++i) m = fmaxf(m, active[i] ? gated[i] : -INFINITY);
            m = fmaxf(m, __shfl_xor(m, 1, 8));
            m = fmaxf(m, __shfl_xor(m, 2, 8));
            m = fmaxf(m, __shfl_xor(m, 4, 8));
            float s = 0.f;
#pragma unroll
            for (int i = 0; i < 8; ++i) {
                float ev = active[i] ? expf(gated[i] - m) : 0.f;
                probs[i] = ev; s += ev;
            }
            s += __shfl_xor(s, 1, 8);
            s += __shfl_xor(s, 2, 8);
            s += __shfl_xor(s, 4, 8);
            float rs = 1.0f / s;
#pragma unroll
            for (int i = 0; i < 8; ++i) {
                probs[i] *= rs;
                mask[i] = active[i] ? 1.f : 0.f;
            }
        } else {
            unsigned key[8];
#pragma unroll
            for (int i = 0; i < 8; ++i) {
                unsigned u = __float_as_uint(logit[i]);
                key[i] = (u & 0x80000000u) ? ~u : (u | 0x80000000u);
            }
            unsigned cand = 0u;
            for (int bit = 31; bit >= 0; --bit) {
                unsigned test = cand | (1u << bit);
                int c = 0;
#pragma unroll
                for (int i = 0; i < 8; ++i) c += (key[i] >= test);
                c += __shfl_xor(c, 1, 8);
                c += __shfl_xor(c, 2, 8);
                c += __shfl_xor(c, 4, 8);
                if (c >= 32) cand = test;
            }
            int cgt = 0;
#pragma unroll
            for (int i = 0; i < 8; ++i) cgt += (key[i] > cand);
            cgt += __shfl_xor(cgt, 1, 8);
            cgt += __shfl_xor(cgt, 2, 8);
            cgt += __shfl_xor(cgt, 4, 8);
            int need_eq = 32 - cgt;

            int eqc = 0;
#pragma unroll
            for (int i = 0; i < 8; ++i) eqc += (key[i] == cand);
            int scan = eqc, tmp;
            tmp = __shfl_up(scan, 1, 8); if (g_e >= 1) scan += tmp;
            tmp = __shfl_up(scan, 2, 8); if (g_e >= 2) scan += tmp;
            tmp = __shfl_up(scan, 4, 8); if (g_e >= 4) scan += tmp;
            int run = scan - eqc;
#pragma unroll
            for (int i = 0; i < 8; ++i) {
                int sel = (key[i] > cand) || ((key[i] == cand) && (run < need_eq));
                run += (key[i] == cand);
                mask[i]  = sel ? 1.f : 0.f;
                probs[i] = sel ? 0.03125f : 0.f;
            }
        }

        size_t row = (size_t)(base_t + t) * NEXP + e0;
        *(float4*)&out[row]                = make_float4(probs[0], probs[1], probs[2], probs[3]);
        *(float4*)&out[row + 4]            = make_float4(probs[4], probs[5], probs[6], probs[7]);
        *(float4*)&out[out_pre + row]      = make_float4(pre[0], pre[1], pre[2], pre[3]);
        *(float4*)&out[out_pre + row + 4]  = make_float4(pre[4], pre[5], pre[6], pre[7]);
        *(float4*)&out[out_mask + row]     = make_float4(mask[0], mask[1], mask[2], mask[3]);
        *(float4*)&out[out_mask + row + 4] = make_float4(mask[4], mask[5], mask[6], mask[7]);
    }
}

extern "C" void kernel_launch(void* const* d_in, const int* in_sizes, int n_in,
                              void* d_out, int out_size, void* d_ws, size_t ws_size,
                              hipStream_t stream) {
    (void)in_sizes; (void)n_in; (void)out_size;
    const float* x     = (const float*)d_in[0];
    const float* sim   = (const float*)d_in[1];
    const float* gates = (const float*)d_in[2];
    float* out = (float*)d_out;
    float* ws  = (float*)d_ws;

    hipLaunchKernelGGL(prep_kernel, dim3(1), dim3(256), 0, stream, sim, gates, ws);

    const size_t need = 512 + (size_t)HID * NEXP * sizeof(float);   // prep + wn2
    if (ws_size >= need) {
        float* wn2 = ws + 128;
        hipLaunchKernelGGL(prep2_kernel, dim3(HID * NEXP / 256), dim3(256), 0, stream,
                           sim, ws, wn2);
        hipLaunchKernelGGL(gate_wave_kernel, dim3(N_TOK / 64), dim3(512), 0, stream,
                           x, wn2, ws, out);
    } else {
        hipLaunchKernelGGL(gate_kernel_fb, dim3(N_TOK / TOKB), dim3(256), 0, stream,
                           x, sim, ws, out);
    }
}

// Round 5
// 216.684 us; speedup vs baseline: 2.1147x; 1.8300x over previous
//
#include <hip/hip_runtime.h>
#include <math.h>

#define N_TOK   65536
#define HID     1024
#define NEXP    64
#define EPSF    1e-12f

// ---------------- prep: ws[0..63] = 1/||sim col||, ws[64..127] = sigmoid(gates)
__global__ __launch_bounds__(256) void prep_kernel(const float* __restrict__ sim,
                                                   const float* __restrict__ gates,
                                                   float* __restrict__ ws) {
    __shared__ float partial[4][64];
    int e = threadIdx.x & 63;
    int q = threadIdx.x >> 6;   // 0..3
    float s = 0.f;
    for (int h = q * 256; h < q * 256 + 256; ++h) {
        float v = sim[h * NEXP + e];
        s += v * v;
    }
    partial[q][e] = s;
    __syncthreads();
    if (threadIdx.x < 64) {
        float ss = partial[0][e] + partial[1][e] + partial[2][e] + partial[3][e];
        ws[e] = 1.0f / fmaxf(sqrtf(ss), EPSF);
        ws[64 + e] = 1.0f / (1.0f + expf(-gates[e]));
    }
}

// ---------------- prep2: natural-layout normalized W: wn[k*64+e] = sim[k*64+e]*invcol[e]
// (single f32 mul, identical rounding to all passing rounds)
__global__ __launch_bounds__(256) void prep2n_kernel(const float* __restrict__ sim,
                                                     const float* __restrict__ ws_ro,
                                                     float* __restrict__ wn) {
    int idx = blockIdx.x * 256 + threadIdx.x;   // 0..65535
    wn[idx] = sim[idx] * ws_ro[idx & 63];
}

// encode float -> order-preserving uint key (and exact inverse)
__device__ __forceinline__ unsigned enc_key(float f) {
    unsigned u = __float_as_uint(f);
    return (u & 0x80000000u) ? ~u : (u | 0x80000000u);
}
__device__ __forceinline__ float dec_key(unsigned k) {
    unsigned u = (k & 0x80000000u) ? (k ^ 0x80000000u) : ~k;
    return __uint_as_float(u);
}

// ---------------- main kernel: 64 threads (1 wave) per block, 64 tokens/block.
// Thread tile: 8 tok x 8 exp. x via transposed LDS (ds_read_b128, 2-way free),
// W via VMEM float4 (L1/L2-resident), acc in VGPRs. No barriers (single wave).
__global__ __launch_bounds__(64) void gate_v5_kernel(const float* __restrict__ x,
                                                     const float* __restrict__ wn,
                                                     const float* __restrict__ prep,
                                                     float* __restrict__ out) {
    __shared__ __align__(16) float xs[2][32][68];       // [buf][k][tok(64)+pad4]
    __shared__ __align__(16) float logits_l[64][68];    // raw dot products
    __shared__ float thr_l[64];

    const int lane  = threadIdx.x;          // 0..63, = local token for staging/epilogue
    const int tbase = blockIdx.x * 64;
    const int tg = lane >> 3;               // token group: tokens tg*8..tg*8+7
    const int eg = lane & 7;                // expert group: experts eg*8..eg*8+7
    const int e0 = eg * 8;

    thr_l[lane] = prep[64 + lane];

    const float4* xq4 = (const float4*)(x + (size_t)(tbase + lane) * HID);

    float acc[8][8];
#pragma unroll
    for (int t = 0; t < 8; ++t)
#pragma unroll
        for (int e = 0; e < 8; ++e) acc[t][e] = 0.f;
    float ss = 0.f;

    // ---- prologue: stage chunk 0 (k 0..31 of own token row), fuse ss ----
    {
        float4 st[8];
#pragma unroll
        for (int q = 0; q < 8; ++q) st[q] = xq4[q];
#pragma unroll
        for (int q = 0; q < 8; ++q) {
            ss = fmaf(st[q].x, st[q].x, ss);
            ss = fmaf(st[q].y, st[q].y, ss);
            ss = fmaf(st[q].z, st[q].z, ss);
            ss = fmaf(st[q].w, st[q].w, ss);
            xs[0][q * 4 + 0][lane] = st[q].x;
            xs[0][q * 4 + 1][lane] = st[q].y;
            xs[0][q * 4 + 2][lane] = st[q].z;
            xs[0][q * 4 + 3][lane] = st[q].w;
        }
    }

#define FMA8x8(XA, XB, WA, WB)                                              \
    do {                                                                    \
        const float xv_[8] = { XA.x, XA.y, XA.z, XA.w, XB.x, XB.y, XB.z, XB.w }; \
        const float wv_[8] = { WA.x, WA.y, WA.z, WA.w, WB.x, WB.y, WB.z, WB.w }; \
        _Pragma("unroll")                                                   \
        for (int t_ = 0; t_ < 8; ++t_)                                      \
            _Pragma("unroll")                                               \
            for (int e_ = 0; e_ < 8; ++e_)                                  \
                acc[t_][e_] = fmaf(xv_[t_], wv_[e_], acc[t_][e_]);          \
    } while (0)

#pragma unroll 1
    for (int c = 0; c < 32; ++c) {
        const int buf = c & 1;
        // issue next chunk's global x loads early (consumed after compute)
        float4 st[8];
        if (c < 31) {
#pragma unroll
            for (int q = 0; q < 8; ++q) st[q] = xq4[(c + 1) * 8 + q];
        }

        const float* wbase = wn + (size_t)c * 32 * NEXP + e0;
        const float (*xb)[68] = xs[buf];

        // W prefetch pipeline, depth 2 k-steps
        float4 a0 = *(const float4*)(wbase + 0 * 64);
        float4 b0 = *(const float4*)(wbase + 0 * 64 + 4);
        float4 a1 = *(const float4*)(wbase + 1 * 64);
        float4 b1 = *(const float4*)(wbase + 1 * 64 + 4);

#pragma unroll 4
        for (int k = 0; k < 32; k += 2) {
            float4 na0, nb0, na1, nb1;
            if (k + 2 < 32) {
                na0 = *(const float4*)(wbase + (k + 2) * 64);
                nb0 = *(const float4*)(wbase + (k + 2) * 64 + 4);
                na1 = *(const float4*)(wbase + (k + 3) * 64);
                nb1 = *(const float4*)(wbase + (k + 3) * 64 + 4);
            }
            const float4 xa0 = *(const float4*)&xb[k][tg * 8];
            const float4 xb0 = *(const float4*)&xb[k][tg * 8 + 4];
            const float4 xa1 = *(const float4*)&xb[k + 1][tg * 8];
            const float4 xb1 = *(const float4*)&xb[k + 1][tg * 8 + 4];
            FMA8x8(xa0, xb0, a0, b0);
            FMA8x8(xa1, xb1, a1, b1);
            a0 = na0; b0 = nb0; a1 = na1; b1 = nb1;
        }

        // write staged chunk c+1 into the other buffer, fuse ss (k-ascending)
        if (c < 31) {
            const int nb = buf ^ 1;
#pragma unroll
            for (int q = 0; q < 8; ++q) {
                ss = fmaf(st[q].x, st[q].x, ss);
                ss = fmaf(st[q].y, st[q].y, ss);
                ss = fmaf(st[q].z, st[q].z, ss);
                ss = fmaf(st[q].w, st[q].w, ss);
                xs[nb][q * 4 + 0][lane] = st[q].x;
                xs[nb][q * 4 + 1][lane] = st[q].y;
                xs[nb][q * 4 + 2][lane] = st[q].z;
                xs[nb][q * 4 + 3][lane] = st[q].w;
            }
        }
    }
#undef FMA8x8

    // ---- dump raw dot products to LDS (single wave: DS is in-order, no barrier)
#pragma unroll
    for (int i = 0; i < 8; ++i) {
        float* p = &logits_l[tg * 8 + i][e0];
        *(float4*)(p)     = make_float4(acc[i][0], acc[i][1], acc[i][2], acc[i][3]);
        *(float4*)(p + 4) = make_float4(acc[i][4], acc[i][5], acc[i][6], acc[i][7]);
    }

    // ---- epilogue: lane owns token (tbase+lane); logits = dot * inv(own ss) ----
    const float inv = 1.0f / fmaxf(sqrtf(ss), EPSF);
    const size_t out_pre  = (size_t)N_TOK * NEXP;
    const size_t out_mask = 2 * (size_t)N_TOK * NEXP;
    const size_t row = (size_t)(tbase + lane) * NEXP;

    unsigned key[64];
    int nact = 0;
#pragma unroll
    for (int e4 = 0; e4 < 64; e4 += 4) {
        float4 lg = *(const float4*)&logits_l[lane][e4];
        lg.x *= inv; lg.y *= inv; lg.z *= inv; lg.w *= inv;
        float4 pr = make_float4(lg.x - thr_l[e4 + 0], lg.y - thr_l[e4 + 1],
                                lg.z - thr_l[e4 + 2], lg.w - thr_l[e4 + 3]);
        *(float4*)&out[out_pre + row + e4] = pr;
        nact += (pr.x > 0.f) + (pr.y > 0.f) + (pr.z > 0.f) + (pr.w > 0.f);
        key[e4 + 0] = enc_key(lg.x);
        key[e4 + 1] = enc_key(lg.y);
        key[e4 + 2] = enc_key(lg.z);
        key[e4 + 3] = enc_key(lg.w);
    }

    if (nact == 0) {
        // top-32 fallback: exact 32nd-largest via radix descent (round-2-proven)
        unsigned cand = 0u;
#pragma unroll 1
        for (int bit = 31; bit >= 0; --bit) {
            unsigned test = cand | (1u << bit);
            int c = 0;
#pragma unroll
            for (int e = 0; e < NEXP; ++e) c += (key[e] >= test);
            if (c >= 32) cand = test;
        }
        int need = 32;
#pragma unroll
        for (int e = 0; e < NEXP; ++e) need -= (key[e] > cand);

#pragma unroll
        for (int e4 = 0; e4 < 64; e4 += 4) {
            float p[4], mk[4];
#pragma unroll
            for (int j = 0; j < 4; ++j) {
                bool gt = key[e4 + j] > cand;
                bool eq = key[e4 + j] == cand;
                bool sel = gt || (eq && need > 0);
                need -= eq ? 1 : 0;
                mk[j] = sel ? 1.f : 0.f;
                p[j]  = sel ? 0.03125f : 0.f;   // gated==0 on fallback rows
            }
            *(float4*)&out[row + e4]            = make_float4(p[0], p[1], p[2], p[3]);
            *(float4*)&out[out_mask + row + e4] = make_float4(mk[0], mk[1], mk[2], mk[3]);
        }
    } else {
        float m = -INFINITY;
#pragma unroll
        for (int e = 0; e < NEXP; ++e) {
            float pr = dec_key(key[e]) - thr_l[e];
            if (pr > 0.f) m = fmaxf(m, pr);
        }
        float s = 0.f;
#pragma unroll
        for (int e = 0; e < NEXP; ++e) {
            float pr = dec_key(key[e]) - thr_l[e];
            s += (pr > 0.f) ? expf(pr - m) : 0.f;
        }
        const float rs = 1.0f / s;
#pragma unroll
        for (int e4 = 0; e4 < 64; e4 += 4) {
            float p[4], mk[4];
#pragma unroll
            for (int j = 0; j < 4; ++j) {
                float pr = dec_key(key[e4 + j]) - thr_l[e4 + j];
                bool a = pr > 0.f;
                p[j]  = a ? expf(pr - m) * rs : 0.f;
                mk[j] = a ? 1.f : 0.f;
            }
            *(float4*)&out[row + e4]            = make_float4(p[0], p[1], p[2], p[3]);
            *(float4*)&out[out_mask + row + e4] = make_float4(mk[0], mk[1], mk[2], mk[3]);
        }
    }
}

// ---------------- fallback (verbatim round-1 kernel, used only if ws too small)
#define TOKB    128
#define KC      64
#define XPAD    65

__global__ __launch_bounds__(256) void gate_kernel_fb(const float* __restrict__ x,
                                                      const float* __restrict__ sim,
                                                      const float* __restrict__ prep,
                                                      float* __restrict__ out) {
    __shared__ float x_lds[TOKB][XPAD];
    __shared__ float w_lds[KC][NEXP];
    __shared__ float ss_lds[TOKB];
    __shared__ float invcol[NEXP];
    __shared__ float thr_s[NEXP];

    const int tid = threadIdx.x;
    const int base_t = blockIdx.x * TOKB;

    if (tid < NEXP) { invcol[tid] = prep[tid]; thr_s[tid] = prep[64 + tid]; }
    if (tid < TOKB) ss_lds[tid] = 0.f;

    const int g_e = tid & 7;
    const int g_t = tid >> 3;
    const int e0 = g_e * 8;
    const int t0 = g_t * 4;

    const int lt = tid >> 4;
    const int lk = (tid & 15) * 4;

    float acc[4][8];
#pragma unroll
    for (int j = 0; j < 4; ++j)
#pragma unroll
        for (int i = 0; i < 8; ++i) acc[j][i] = 0.f;

    for (int kc = 0; kc < HID; kc += KC) {
        __syncthreads();
#pragma unroll
        for (int it = 0; it < 4; ++it) {
            int flat4 = it * 256 + tid;
            int k = flat4 >> 4;
            int e = (flat4 & 15) * 4;
            float4 v = *(const float4*)&sim[(size_t)(kc + k) * NEXP + e];
            v.x *= invcol[e]; v.y *= invcol[e + 1]; v.z *= invcol[e + 2]; v.w *= invcol[e + 3];
            *(float4*)&w_lds[k][e] = v;
        }
#pragma unroll
        for (int it = 0; it < 8; ++it) {
            int t = it * 16 + lt;
            float4 v = *(const float4*)&x[(size_t)(base_t + t) * HID + kc + lk];
            x_lds[t][lk + 0] = v.x; x_lds[t][lk + 1] = v.y;
            x_lds[t][lk + 2] = v.z; x_lds[t][lk + 3] = v.w;
            float s4 = v.x * v.x + v.y * v.y + v.z * v.z + v.w * v.w;
            s4 += __shfl_xor(s4, 1, 16);
            s4 += __shfl_xor(s4, 2, 16);
            s4 += __shfl_xor(s4, 4, 16);
            s4 += __shfl_xor(s4, 8, 16);
            if ((tid & 15) == 0) ss_lds[t] += s4;
        }
        __syncthreads();
#pragma unroll 8
        for (int k = 0; k < KC; ++k) {
            float x0 = x_lds[t0 + 0][k];
            float x1 = x_lds[t0 + 1][k];
            float x2 = x_lds[t0 + 2][k];
            float x3 = x_lds[t0 + 3][k];
            float4 w0 = *(const float4*)&w_lds[k][e0];
            float4 w1 = *(const float4*)&w_lds[k][e0 + 4];
            float wv[8] = { w0.x, w0.y, w0.z, w0.w, w1.x, w1.y, w1.z, w1.w };
#pragma unroll
            for (int i = 0; i < 8; ++i) {
                acc[0][i] += x0 * wv[i];
                acc[1][i] += x1 * wv[i];
                acc[2][i] += x2 * wv[i];
                acc[3][i] += x3 * wv[i];
            }
        }
    }

    const size_t out_pre  = (size_t)N_TOK * NEXP;
    const size_t out_mask = 2 * (size_t)N_TOK * NEXP;

#pragma unroll
    for (int j = 0; j < 4; ++j) {
        int t = t0 + j;
        float inv = 1.0f / fmaxf(sqrtf(ss_lds[t]), EPSF);
        float logit[8], pre[8], gated[8];
        int active[8];
        int myact = 0;
#pragma unroll
        for (int i = 0; i < 8; ++i) {
            logit[i] = acc[j][i] * inv;
            pre[i]   = logit[i] - thr_s[e0 + i];
            gated[i] = fmaxf(pre[i], 0.f);
            active[i] = pre[i] > 0.f;
            myact += active[i];
        }
        int rowact = myact;
        rowact += __shfl_xor(rowact, 1, 8);
        rowact += __shfl_xor(rowact, 2, 8);
        rowact += __shfl_xor(rowact, 4, 8);

        float probs[8], mask[8];
        if (rowact > 0) {
            float m = -INFINITY;
#pragma unroll
            for (int i = 0; i < 8; ++i) m = fmaxf(m, active[i] ? gated[i] : -INFINITY);
            m = fmaxf(m, __shfl_xor(m, 1, 8));
            m = fmaxf(m, __shfl_xor(m, 2, 8));
            m = fmaxf(m, __shfl_xor(m, 4, 8));
            float s = 0.f;
#pragma unroll
            for (int i = 0; i < 8; ++i) {
                float ev = active[i] ? expf(gated[i] - m) : 0.f;
                probs[i] = ev; s += ev;
            }
            s += __shfl_xor(s, 1, 8);
            s += __shfl_xor(s, 2, 8);
            s += __shfl_xor(s, 4, 8);
            float rs = 1.0f / s;
#pragma unroll
            for (int i = 0; i < 8; ++i) {
                probs[i] *= rs;
                mask[i] = active[i] ? 1.f : 0.f;
            }
        } else {
            unsigned key[8];
#pragma unroll
            for (int i = 0; i < 8; ++i) {
                unsigned u = __float_as_uint(logit[i]);
                key[i] = (u & 0x80000000u) ? ~u : (u | 0x80000000u);
            }
            unsigned cand = 0u;
            for (int bit = 31; bit >= 0; --bit) {
                unsigned test = cand | (1u << bit);
                int c = 0;
#pragma unroll
                for (int i = 0; i < 8; ++i) c += (key[i] >= test);
                c += __shfl_xor(c, 1, 8);
                c += __shfl_xor(c, 2, 8);
                c += __shfl_xor(c, 4, 8);
                if (c >= 32) cand = test;
            }
            int cgt = 0;
#pragma unroll
            for (int i = 0; i < 8; ++i) cgt += (key[i] > cand);
            cgt += __shfl_xor(cgt, 1, 8);
            cgt += __shfl_xor(cgt, 2, 8);
            cgt += __shfl_xor(cgt, 4, 8);
            int need_eq = 32 - cgt;

            int eqc = 0;
#pragma unroll
            for (int i = 0; i < 8; ++i) eqc += (key[i] == cand);
            int scan = eqc, tmp;
            tmp = __shfl_up(scan, 1, 8); if (g_e >= 1) scan += tmp;
            tmp = __shfl_up(scan, 2, 8); if (g_e >= 2) scan += tmp;
            tmp = __shfl_up(scan, 4, 8); if (g_e >= 4) scan += tmp;
            int run = scan - eqc;
#pragma unroll
            for (int i = 0; i < 8; ++i) {
                int sel = (key[i] > cand) || ((key[i] == cand) && (run < need_eq));
                run += (key[i] == cand);
                mask[i]  = sel ? 1.f : 0.f;
                probs[i] = sel ? 0.03125f : 0.f;
            }
        }

        size_t row = (size_t)(base_t + t) * NEXP + e0;
        *(float4*)&out[row]                = make_float4(probs[0], probs[1], probs[2], probs[3]);
        *(float4*)&out[row + 4]            = make_float4(probs[4], probs[5], probs[6], probs[7]);
        *(float4*)&out[out_pre + row]      = make_float4(pre[0], pre[1], pre[2], pre[3]);
        *(float4*)&out[out_pre + row + 4]  = make_float4(pre[4], pre[5], pre[6], pre[7]);
        *(float4*)&out[out_mask + row]     = make_float4(mask[0], mask[1], mask[2], mask[3]);
        *(float4*)&out[out_mask + row + 4] = make_float4(mask[4], mask[5], mask[6], mask[7]);
    }
}

extern "C" void kernel_launch(void* const* d_in, const int* in_sizes, int n_in,
                              void* d_out, int out_size, void* d_ws, size_t ws_size,
                              hipStream_t stream) {
    (void)in_sizes; (void)n_in; (void)out_size;
    const float* x     = (const float*)d_in[0];
    const float* sim   = (const float*)d_in[1];
    const float* gates = (const float*)d_in[2];
    float* out = (float*)d_out;
    float* ws  = (float*)d_ws;

    hipLaunchKernelGGL(prep_kernel, dim3(1), dim3(256), 0, stream, sim, gates, ws);

    const size_t need = 512 + (size_t)HID * NEXP * sizeof(float);   // prep + wn
    if (ws_size >= need) {
        float* wn = ws + 128;
        hipLaunchKernelGGL(prep2n_kernel, dim3(HID * NEXP / 256), dim3(256), 0, stream,
                           sim, ws, wn);
        hipLaunchKernelGGL(gate_v5_kernel, dim3(N_TOK / 64), dim3(64), 0, stream,
                           x, wn, ws, out);
    } else {
        hipLaunchKernelGGL(gate_kernel_fb, dim3(N_TOK / TOKB), dim3(256), 0, stream,
                           x, sim, ws, out);
    }
}